// Round 1
// baseline (142.826 us; speedup 1.0000x reference)
//
#include <hip/hip_runtime.h>
#include <stdint.h>

// RBF layer: out[b,c] = exp(-gamma * sqrt(max(||x_b||^2 - 2 x_b.c_c + ||c_c||^2, 0)))
// B=16384, D=1024, C=2048 (fp32 in/out).
// Strategy: bf16 MFMA GEMM (m97-structure: 128x128 tile, BK=32, global_load_lds w=16)
// with fp32 row-norms computed from the original fp32 data; fused sqrt/exp epilogue.

typedef __attribute__((ext_vector_type(8))) short bf16x8;
typedef __attribute__((ext_vector_type(4))) float f32x4;

#define BM 128
#define BN 128
#define BK 32

__device__ __forceinline__ unsigned short f2bf(float f) {
  union { float f; unsigned int u; } c; c.f = f;
  unsigned int u = c.u;
  unsigned int r = (u + 0x7fffu + ((u >> 16) & 1u)) >> 16;  // RNE
  return (unsigned short)r;
}

// One block per row: fp32 -> bf16 convert + fp32 sum-of-squares.
__global__ __launch_bounds__(256) void prep_rows(
    const float* __restrict__ in, unsigned short* __restrict__ ob,
    float* __restrict__ norm, int K) {
  int row = blockIdx.x;
  const float4* rp = (const float4*)(in + (size_t)row * K);
  ushort4* op = (ushort4*)(ob + (size_t)row * K);
  float s = 0.f;
  for (int i = threadIdx.x; i < (K >> 2); i += blockDim.x) {
    float4 v = rp[i];
    s += v.x * v.x + v.y * v.y + v.z * v.z + v.w * v.w;
    ushort4 u;
    u.x = f2bf(v.x); u.y = f2bf(v.y); u.z = f2bf(v.z); u.w = f2bf(v.w);
    op[i] = u;
  }
  for (int off = 32; off > 0; off >>= 1) s += __shfl_down(s, off, 64);
  __shared__ float partial[4];
  int lane = threadIdx.x & 63, wv = threadIdx.x >> 6;
  if (lane == 0) partial[wv] = s;
  __syncthreads();
  if (threadIdx.x == 0) {
    float t = 0.f;
    int nw = (blockDim.x + 63) >> 6;
    for (int w = 0; w < nw; ++w) t += partial[w];
    norm[row] = t;
  }
}

// m97-structure bf16 GEMM: C[row,col] = dot(x_row, cent_col) with fused RBF epilogue.
// A: [M][K] bf16 row-major (x). Bm: [N][K] bf16 row-major (centers). Both stride-K.
__global__ __launch_bounds__(256) void rbf_gemm(
    const unsigned short* __restrict__ A, const unsigned short* __restrict__ Bm,
    const float* __restrict__ x2, const float* __restrict__ c2,
    const float* __restrict__ gamma, float* __restrict__ out,
    int M, int N, int K) {
  __shared__ __align__(16) unsigned short As[BM][BK];
  __shared__ __align__(16) unsigned short Bs[BN][BK];

  int nbn = N / BN;
  int nwg = (M / BM) * nbn;
  int bid = blockIdx.x;
  int wg = bid;
  if ((nwg & 7) == 0) {  // XCD-aware swizzle (bijective since nwg % 8 == 0)
    int cpx = nwg >> 3;
    wg = (bid & 7) * cpx + (bid >> 3);
  }
  int bm = wg / nbn, bn = wg % nbn;

  int tid = threadIdx.x;
  int lane = tid & 63, wv = tid >> 6;
  int wr = wv >> 1, wc = wv & 1;  // 2x2 waves over the 128x128 tile

  const unsigned short* Ab = A + (size_t)bm * BM * K;
  const unsigned short* Bb = Bm + (size_t)bn * BN * K;

  int r0 = tid >> 2;        // staging row 0..63 (and +64)
  int c0 = (tid & 3) * 8;   // staging k-offset (elements)

  f32x4 acc[4][4];
#pragma unroll
  for (int m = 0; m < 4; ++m)
#pragma unroll
    for (int n = 0; n < 4; ++n) acc[m][n] = (f32x4){0.f, 0.f, 0.f, 0.f};

  int arow = wr * 64 + (lane & 15);
  int brow = wc * 64 + (lane & 15);
  int k8 = (lane >> 4) * 8;

  for (int kt = 0; kt < K; kt += BK) {
    __builtin_amdgcn_global_load_lds(
        (const __attribute__((address_space(1))) unsigned int*)(Ab + (size_t)r0 * K + kt + c0),
        (__attribute__((address_space(3))) unsigned int*)&As[r0][c0], 16, 0, 0);
    __builtin_amdgcn_global_load_lds(
        (const __attribute__((address_space(1))) unsigned int*)(Ab + (size_t)(r0 + 64) * K + kt + c0),
        (__attribute__((address_space(3))) unsigned int*)&As[r0 + 64][c0], 16, 0, 0);
    __builtin_amdgcn_global_load_lds(
        (const __attribute__((address_space(1))) unsigned int*)(Bb + (size_t)r0 * K + kt + c0),
        (__attribute__((address_space(3))) unsigned int*)&Bs[r0][c0], 16, 0, 0);
    __builtin_amdgcn_global_load_lds(
        (const __attribute__((address_space(1))) unsigned int*)(Bb + (size_t)(r0 + 64) * K + kt + c0),
        (__attribute__((address_space(3))) unsigned int*)&Bs[r0 + 64][c0], 16, 0, 0);
    __syncthreads();  // compiler drains vmcnt before barrier

    bf16x8 af[4], bfv[4];
#pragma unroll
    for (int m = 0; m < 4; ++m) af[m] = *(const bf16x8*)&As[arow + m * 16][k8];
#pragma unroll
    for (int n = 0; n < 4; ++n) bfv[n] = *(const bf16x8*)&Bs[brow + n * 16][k8];
#pragma unroll
    for (int m = 0; m < 4; ++m)
#pragma unroll
      for (int n = 0; n < 4; ++n)
        acc[m][n] = __builtin_amdgcn_mfma_f32_16x16x32_bf16(af[m], bfv[n], acc[m][n], 0, 0, 0);
    __syncthreads();
  }

  // Epilogue: C/D layout col = lane&15, row = (lane>>4)*4 + reg  [m89/m91-verified]
  float g = gamma[0];
  int rb = bm * BM + wr * 64 + (lane >> 4) * 4;
  int cbase = bn * BN + wc * 64 + (lane & 15);
#pragma unroll
  for (int m = 0; m < 4; ++m) {
#pragma unroll
    for (int j = 0; j < 4; ++j) {
      int row = rb + m * 16 + j;
      float xr = x2[row];
      size_t ob = (size_t)row * N;
#pragma unroll
      for (int n = 0; n < 4; ++n) {
        int col = cbase + n * 16;
        float sq = fmaxf(xr + c2[col] - 2.f * acc[m][n][j], 0.f);
        out[ob + col] = __expf(-g * __builtin_sqrtf(sq));
      }
    }
  }
}

// Correctness fallback if workspace is too small (slow, fp32 vector path).
__global__ __launch_bounds__(256) void rbf_naive(
    const float* __restrict__ x, const float* __restrict__ cent,
    const float* __restrict__ gamma, float* __restrict__ out, int D, int N) {
  int row = blockIdx.x;
  int col = blockIdx.y * blockDim.x + threadIdx.x;
  extern __shared__ float xs[];
  for (int i = threadIdx.x; i < D; i += blockDim.x)
    xs[i] = x[(size_t)row * D + i];
  __syncthreads();
  if (col >= N) return;
  const float* cp = cent + (size_t)col * D;
  float s = 0.f;
  for (int d = 0; d < D; ++d) {
    float df = xs[d] - cp[d];
    s += df * df;
  }
  out[(size_t)row * N + col] = __expf(-gamma[0] * __builtin_sqrtf(fmaxf(s, 0.f)));
}

extern "C" void kernel_launch(void* const* d_in, const int* in_sizes, int n_in,
                              void* d_out, int out_size, void* d_ws, size_t ws_size,
                              hipStream_t stream) {
  const float* x = (const float*)d_in[0];
  const float* cent = (const float*)d_in[1];
  const float* gamma = (const float*)d_in[2];
  float* out = (float*)d_out;

  const int D = 1024;  // feature dim per the reference
  int Brows = in_sizes[0] / D;
  int C = in_sizes[1] / D;

  size_t xb_bytes = (size_t)Brows * D * 2;
  size_t cb_bytes = (size_t)C * D * 2;
  size_t need = xb_bytes + cb_bytes + (size_t)Brows * 4 + (size_t)C * 4;
  bool can = (ws_size >= need) && (Brows % BM == 0) && (C % BN == 0) && (D % BK == 0);

  if (!can) {
    dim3 grid(Brows, (C + 255) / 256);
    hipLaunchKernelGGL(rbf_naive, grid, dim3(256), D * sizeof(float), stream,
                       x, cent, gamma, out, D, C);
    return;
  }

  unsigned short* xb = (unsigned short*)d_ws;
  unsigned short* cb = (unsigned short*)((char*)d_ws + xb_bytes);
  float* x2 = (float*)((char*)d_ws + xb_bytes + cb_bytes);
  float* c2 = x2 + Brows;

  hipLaunchKernelGGL(prep_rows, dim3(Brows), dim3(256), 0, stream, x, xb, x2, D);
  hipLaunchKernelGGL(prep_rows, dim3(C), dim3(256), 0, stream, cent, cb, c2, D);

  int nwg = (Brows / BM) * (C / BN);
  hipLaunchKernelGGL(rbf_gemm, dim3(nwg), dim3(256), 0, stream,
                     xb, cb, x2, c2, gamma, out, Brows, C, D);
}

// Round 2
// 122.284 us; speedup vs baseline: 1.1680x; 1.1680x over previous
//
#include <hip/hip_runtime.h>
#include <stdint.h>

// RBF layer: out[b,c] = exp(-gamma * sqrt(max(||x_b||^2 - 2 x_b.c_c + ||c_c||^2, 0)))
// B=16384, D=1024, C=2048 (fp32 in/out).
// bf16 MFMA GEMM, 128x128 tile, BK=64, global_load_lds w=16,
// T2 XOR-swizzle (slot ^= row&7) via pre-swizzled global source + swizzled ds_read.
// fp32 row-norms from original fp32 data; fused sqrt/exp epilogue.

typedef __attribute__((ext_vector_type(8))) short bf16x8;
typedef __attribute__((ext_vector_type(4))) float f32x4;

#define BM 128
#define BN 128
#define BK 64

__device__ __forceinline__ unsigned short f2bf(float f) {
  union { float f; unsigned int u; } c; c.f = f;
  unsigned int u = c.u;
  unsigned int r = (u + 0x7fffu + ((u >> 16) & 1u)) >> 16;  // RNE
  return (unsigned short)r;
}

// One block per row: fp32 -> bf16 convert + fp32 sum-of-squares.
__global__ __launch_bounds__(256) void prep_rows(
    const float* __restrict__ in, unsigned short* __restrict__ ob,
    float* __restrict__ norm, int K) {
  int row = blockIdx.x;
  const float4* rp = (const float4*)(in + (size_t)row * K);
  ushort4* op = (ushort4*)(ob + (size_t)row * K);
  float s = 0.f;
  for (int i = threadIdx.x; i < (K >> 2); i += blockDim.x) {
    float4 v = rp[i];
    s += v.x * v.x + v.y * v.y + v.z * v.z + v.w * v.w;
    ushort4 u;
    u.x = f2bf(v.x); u.y = f2bf(v.y); u.z = f2bf(v.z); u.w = f2bf(v.w);
    op[i] = u;
  }
  for (int off = 32; off > 0; off >>= 1) s += __shfl_down(s, off, 64);
  __shared__ float partial[4];
  int lane = threadIdx.x & 63, wv = threadIdx.x >> 6;
  if (lane == 0) partial[wv] = s;
  __syncthreads();
  if (threadIdx.x == 0) {
    float t = 0.f;
    int nw = (blockDim.x + 63) >> 6;
    for (int w = 0; w < nw; ++w) t += partial[w];
    norm[row] = t;
  }
}

// bf16 GEMM: dot(x_row, cent_col) with fused RBF epilogue.
// A: [M][K] bf16 row-major (x). Bm: [N][K] bf16 row-major (centers).
__global__ __launch_bounds__(256) void rbf_gemm(
    const unsigned short* __restrict__ A, const unsigned short* __restrict__ Bm,
    const float* __restrict__ x2, const float* __restrict__ c2,
    const float* __restrict__ gamma, float* __restrict__ out,
    int M, int N, int K) {
  // Physical layout: As[row][slot*8..slot*8+7] holds logical k-block (slot ^ (row&7)).
  __shared__ __align__(16) unsigned short As[BM][BK];
  __shared__ __align__(16) unsigned short Bs[BN][BK];

  int nbn = N / BN;
  int nwg = (M / BM) * nbn;
  int bid = blockIdx.x;
  int wg = bid;
  if ((nwg & 7) == 0) {  // XCD-aware swizzle (bijective since nwg % 8 == 0)
    int cpx = nwg >> 3;
    wg = (bid & 7) * cpx + (bid >> 3);
  }
  int bm = wg / nbn, bn = wg % nbn;

  int tid = threadIdx.x;
  int lane = tid & 63, wv = tid >> 6;
  int wr = wv >> 1, wc = wv & 1;  // 2x2 waves over the 128x128 tile

  const unsigned short* Ab = A + (size_t)bm * BM * K;
  const unsigned short* Bb = Bm + (size_t)bn * BN * K;

  // Staging decomposition: 256 threads x 16B cover 32 rows x 64 cols per inst.
  int r_s = tid >> 3;                 // row within 32-row group
  int s_s = tid & 7;                  // 16B slot 0..7
  int swz_s = s_s ^ (r_s & 7);        // pre-swizzled global slot (row&7 == r_s&7 for all groups)
  int gcol = swz_s * 8;               // element offset within row

  f32x4 acc[4][4];
#pragma unroll
  for (int m = 0; m < 4; ++m)
#pragma unroll
    for (int n = 0; n < 4; ++n) acc[m][n] = (f32x4){0.f, 0.f, 0.f, 0.f};

  int arow0 = wr * 64 + (lane & 15);
  int brow0 = wc * 64 + (lane & 15);
  int lswz = lane & 7;                // (row & 7) for all fragment rows this lane reads

  for (int kt = 0; kt < K; kt += BK) {
#pragma unroll
    for (int i = 0; i < 4; ++i) {
      int row = i * 32 + r_s;
      __builtin_amdgcn_global_load_lds(
          (const __attribute__((address_space(1))) unsigned int*)(Ab + (size_t)row * K + kt + gcol),
          (__attribute__((address_space(3))) unsigned int*)&As[row][s_s * 8], 16, 0, 0);
    }
#pragma unroll
    for (int i = 0; i < 4; ++i) {
      int row = i * 32 + r_s;
      __builtin_amdgcn_global_load_lds(
          (const __attribute__((address_space(1))) unsigned int*)(Bb + (size_t)row * K + kt + gcol),
          (__attribute__((address_space(3))) unsigned int*)&Bs[row][s_s * 8], 16, 0, 0);
    }
    __syncthreads();  // compiler drains vmcnt before barrier

#pragma unroll
    for (int ks = 0; ks < 2; ++ks) {
      int pslot = ((lane >> 4) + ks * 4) ^ lswz;  // physical slot for logical k-block
      bf16x8 af[4], bfv[4];
#pragma unroll
      for (int m = 0; m < 4; ++m) af[m] = *(const bf16x8*)&As[arow0 + m * 16][pslot * 8];
#pragma unroll
      for (int n = 0; n < 4; ++n) bfv[n] = *(const bf16x8*)&Bs[brow0 + n * 16][pslot * 8];
#pragma unroll
      for (int m = 0; m < 4; ++m)
#pragma unroll
        for (int n = 0; n < 4; ++n)
          acc[m][n] = __builtin_amdgcn_mfma_f32_16x16x32_bf16(af[m], bfv[n], acc[m][n], 0, 0, 0);
    }
    __syncthreads();
  }

  // Epilogue: C/D layout col = lane&15, row = (lane>>4)*4 + reg  [m89/m91-verified]
  float g = gamma[0];
  int rb = bm * BM + wr * 64 + (lane >> 4) * 4;
  int cbase = bn * BN + wc * 64 + (lane & 15);
#pragma unroll
  for (int m = 0; m < 4; ++m) {
#pragma unroll
    for (int j = 0; j < 4; ++j) {
      int row = rb + m * 16 + j;
      float xr = x2[row];
      size_t ob = (size_t)row * N;
#pragma unroll
      for (int n = 0; n < 4; ++n) {
        int col = cbase + n * 16;
        float sq = fmaxf(xr + c2[col] - 2.f * acc[m][n][j], 0.f);
        out[ob + col] = __expf(-g * __builtin_sqrtf(sq));
      }
    }
  }
}

// Correctness fallback if workspace is too small (slow, fp32 vector path).
__global__ __launch_bounds__(256) void rbf_naive(
    const float* __restrict__ x, const float* __restrict__ cent,
    const float* __restrict__ gamma, float* __restrict__ out, int D, int N) {
  int row = blockIdx.x;
  int col = blockIdx.y * blockDim.x + threadIdx.x;
  extern __shared__ float xs[];
  for (int i = threadIdx.x; i < D; i += blockDim.x)
    xs[i] = x[(size_t)row * D + i];
  __syncthreads();
  if (col >= N) return;
  const float* cp = cent + (size_t)col * D;
  float s = 0.f;
  for (int d = 0; d < D; ++d) {
    float df = xs[d] - cp[d];
    s += df * df;
  }
  out[(size_t)row * N + col] = __expf(-gamma[0] * __builtin_sqrtf(fmaxf(s, 0.f)));
}

extern "C" void kernel_launch(void* const* d_in, const int* in_sizes, int n_in,
                              void* d_out, int out_size, void* d_ws, size_t ws_size,
                              hipStream_t stream) {
  const float* x = (const float*)d_in[0];
  const float* cent = (const float*)d_in[1];
  const float* gamma = (const float*)d_in[2];
  float* out = (float*)d_out;

  const int D = 1024;  // feature dim per the reference
  int Brows = in_sizes[0] / D;
  int C = in_sizes[1] / D;

  size_t xb_bytes = (size_t)Brows * D * 2;
  size_t cb_bytes = (size_t)C * D * 2;
  size_t need = xb_bytes + cb_bytes + (size_t)Brows * 4 + (size_t)C * 4;
  bool can = (ws_size >= need) && (Brows % BM == 0) && (C % BN == 0) && (D % BK == 0);

  if (!can) {
    dim3 grid(Brows, (C + 255) / 256);
    hipLaunchKernelGGL(rbf_naive, grid, dim3(256), D * sizeof(float), stream,
                       x, cent, gamma, out, D, C);
    return;
  }

  unsigned short* xb = (unsigned short*)d_ws;
  unsigned short* cb = (unsigned short*)((char*)d_ws + xb_bytes);
  float* x2 = (float*)((char*)d_ws + xb_bytes + cb_bytes);
  float* c2 = x2 + Brows;

  hipLaunchKernelGGL(prep_rows, dim3(Brows), dim3(256), 0, stream, x, xb, x2, D);
  hipLaunchKernelGGL(prep_rows, dim3(C), dim3(256), 0, stream, cent, cb, c2, D);

  int nwg = (Brows / BM) * (C / BN);
  hipLaunchKernelGGL(rbf_gemm, dim3(nwg), dim3(256), 0, stream,
                     xb, cb, x2, c2, gamma, out, Brows, C, D);
}

// Round 3
// 108.276 us; speedup vs baseline: 1.3191x; 1.1294x over previous
//
#include <hip/hip_runtime.h>
#include <stdint.h>

// RBF layer: out[b,c] = exp(-gamma * sqrt(max(||x_b||^2 - 2 x_b.c_c + ||c_c||^2, 0)))
// B=16384, D=1024, C=2048 (fp32 in/out).
// bf16 MFMA GEMM, 256x256 tile, BK=32, 3-buffer LDS ring with COUNTED vmcnt(4)
// (never drains in main loop), raw s_barrier, setprio around MFMA clusters,
// slot-rotation LDS swizzle via pre-swizzled global source. fp32 row-norms from
// original fp32 data; fused sqrt/exp epilogue.

typedef __attribute__((ext_vector_type(8))) short bf16x8;
typedef __attribute__((ext_vector_type(4))) float f32x4;

#define BM 256
#define BN 256
#define BK 32

__device__ __forceinline__ unsigned short f2bf(float f) {
  union { float f; unsigned int u; } c; c.f = f;
  unsigned int u = c.u;
  unsigned int r = (u + 0x7fffu + ((u >> 16) & 1u)) >> 16;  // RNE
  return (unsigned short)r;
}

// One block per row: fp32 -> bf16 convert + fp32 sum-of-squares.
__global__ __launch_bounds__(256) void prep_rows(
    const float* __restrict__ in, unsigned short* __restrict__ ob,
    float* __restrict__ norm, int K) {
  int row = blockIdx.x;
  const float4* rp = (const float4*)(in + (size_t)row * K);
  ushort4* op = (ushort4*)(ob + (size_t)row * K);
  float s = 0.f;
  for (int i = threadIdx.x; i < (K >> 2); i += blockDim.x) {
    float4 v = rp[i];
    s += v.x * v.x + v.y * v.y + v.z * v.z + v.w * v.w;
    ushort4 u;
    u.x = f2bf(v.x); u.y = f2bf(v.y); u.z = f2bf(v.z); u.w = f2bf(v.w);
    op[i] = u;
  }
  for (int off = 32; off > 0; off >>= 1) s += __shfl_down(s, off, 64);
  __shared__ float partial[4];
  int lane = threadIdx.x & 63, wv = threadIdx.x >> 6;
  if (lane == 0) partial[wv] = s;
  __syncthreads();
  if (threadIdx.x == 0) {
    float t = 0.f;
    int nw = (blockDim.x + 63) >> 6;
    for (int w = 0; w < nw; ++w) t += partial[w];
    norm[row] = t;
  }
}

#define GLDS(gptr, lptr)                                                      \
  __builtin_amdgcn_global_load_lds(                                           \
      (const __attribute__((address_space(1))) unsigned int*)(gptr),          \
      (__attribute__((address_space(3))) unsigned int*)(lptr), 16, 0, 0)

// 256x256 bf16 GEMM with counted-vmcnt 3-buffer pipeline + fused RBF epilogue.
// A: [M][K] bf16 row-major (x). Bm: [N][K] bf16 row-major (centers).
__global__ __launch_bounds__(512, 2) void rbf_gemm(
    const unsigned short* __restrict__ A, const unsigned short* __restrict__ Bm,
    const float* __restrict__ x2, const float* __restrict__ c2,
    const float* __restrict__ gamma, float* __restrict__ out,
    int M, int N, int K) {
  // 3 buffers x 32KB: per buffer A-tile 16KB (256x32 bf16) then B-tile 16KB.
  // Physical slot p (16B) of row r holds logical slot l where p=(l+(r>>1))&3.
  __shared__ __align__(16) unsigned short lds[3 * 16384];

  int nbn = N / BN;
  int nwg = (M / BM) * nbn;
  int bid = blockIdx.x;
  int wg = bid;
  if ((nwg & 7) == 0) {  // XCD-aware swizzle (bijective: nwg % 8 == 0)
    int cpx = nwg >> 3;
    wg = (bid & 7) * cpx + (bid >> 3);
  }
  int bm = wg / nbn, bn = wg % nbn;

  int tid = threadIdx.x;
  int lane = tid & 63, wv = tid >> 6;
  int wm = wv >> 1;   // 0..3 : wave row (64 rows each)
  int wn = wv & 1;    // 0..1 : wave col (128 cols each)
  int l15 = lane & 15, l4 = lane >> 4;

  // ---- staging map: each gload inst covers 128 rows x 64B (8KB) ----
  // thread -> (row = i*128 + tid>>2, phys slot = tid&3); fetch logical slot:
  int lsw = ((tid & 3) - (tid >> 3)) & 3;
  const unsigned short* AgT =
      A + (size_t)bm * BM * K + (size_t)(tid >> 2) * K + lsw * 8;
  const unsigned short* BgT =
      Bm + (size_t)bn * BN * K + (size_t)(tid >> 2) * K + lsw * 8;
  size_t rstep = (size_t)128 * K;  // second-inst row offset

  // ---- fragment read map (contiguous 1KB per wave -> conflict-free) ----
  int pc = (l4 + (l15 >> 1)) & 3;                     // phys slot for this lane
  int aoff = (wm * 64 + l15) * 32 + pc * 8;           // shorts; + m*512
  int boff = 8192 + (wn * 128 + l15) * 32 + pc * 8;   // shorts; + n*512

  f32x4 acc[4][8];
#pragma unroll
  for (int m = 0; m < 4; ++m)
#pragma unroll
    for (int n = 0; n < 8; ++n) acc[m][n] = (f32x4){0.f, 0.f, 0.f, 0.f};

  int nt = K / BK;

  // ---- prologue: stage tiles 0,1 into buffers 0,1 (order A0,A1,B0,B1) ----
#pragma unroll
  for (int tt = 0; tt < 2; ++tt) {
    unsigned short* base = lds + tt * 16384;
    GLDS(AgT + (size_t)tt * BK, base + tid * 8);
    GLDS(AgT + rstep + (size_t)tt * BK, base + 4096 + tid * 8);
    GLDS(BgT + (size_t)tt * BK, base + 8192 + tid * 8);
    GLDS(BgT + rstep + (size_t)tt * BK, base + 12288 + tid * 8);
  }
  asm volatile("s_waitcnt vmcnt(4)" ::: "memory");  // tile 0 resident
  __builtin_amdgcn_s_barrier();

  int rb = 0;
  for (int t = 0; t < nt; ++t) {
    const unsigned short* bufR = lds + rb * 16384;
    int sbi = rb + 2; if (sbi >= 3) sbi -= 3;
    unsigned short* bufS = lds + sbi * 16384;
    size_t ktS = (size_t)(t + 2) * BK;
    bool doStage = (t + 2 < nt);

    // ================= phase 0: A(m0-3) + B(n0-3), stage A of t+2 =========
    bf16x8 af[4], bfv[4];
#pragma unroll
    for (int m = 0; m < 4; ++m)
      af[m] = *(const bf16x8*)(bufR + aoff + m * 512);
#pragma unroll
    for (int n = 0; n < 4; ++n)
      bfv[n] = *(const bf16x8*)(bufR + boff + n * 512);
    if (doStage) {
      GLDS(AgT + ktS, bufS + tid * 8);
      GLDS(AgT + rstep + ktS, bufS + 4096 + tid * 8);
    }
    __builtin_amdgcn_s_barrier();
    __builtin_amdgcn_s_setprio(1);
#pragma unroll
    for (int m = 0; m < 4; ++m)
#pragma unroll
      for (int n = 0; n < 4; ++n)
        acc[m][n] = __builtin_amdgcn_mfma_f32_16x16x32_bf16(af[m], bfv[n], acc[m][n], 0, 0, 0);
    __builtin_amdgcn_s_setprio(0);
    __builtin_amdgcn_s_barrier();

    // ================= phase 1: B(n4-7) (A cached), stage B of t+2 ========
    bf16x8 bg[4];
#pragma unroll
    for (int n = 0; n < 4; ++n)
      bg[n] = *(const bf16x8*)(bufR + boff + (n + 4) * 512);
    if (doStage) {
      GLDS(BgT + ktS, bufS + 8192 + tid * 8);
      GLDS(BgT + rstep + ktS, bufS + 12288 + tid * 8);
    }
    __builtin_amdgcn_s_barrier();
    __builtin_amdgcn_s_setprio(1);
#pragma unroll
    for (int m = 0; m < 4; ++m)
#pragma unroll
      for (int n = 0; n < 4; ++n)
        acc[m][n + 4] = __builtin_amdgcn_mfma_f32_16x16x32_bf16(af[m], bg[n], acc[m][n + 4], 0, 0, 0);
    __builtin_amdgcn_s_setprio(0);
    // Counted wait: outstanding = S_{t+1}(4) + S_{t+2}(4); vmcnt(4) => S_{t+1} done.
    if (t < nt - 2) {
      asm volatile("s_waitcnt vmcnt(4)" ::: "memory");
    } else if (t == nt - 2) {
      asm volatile("s_waitcnt vmcnt(0)" ::: "memory");
    }
    __builtin_amdgcn_s_barrier();

    rb++; if (rb == 3) rb = 0;
  }

  // ---- epilogue: C/D layout col = lane&15, row = (lane>>4)*4 + reg ----
  float g = gamma[0];
  int rb0 = bm * BM + wm * 64 + l4 * 4;
  int cb0 = bn * BN + wn * 128 + l15;
#pragma unroll
  for (int m = 0; m < 4; ++m) {
#pragma unroll
    for (int j = 0; j < 4; ++j) {
      int row = rb0 + m * 16 + j;
      float xr = x2[row];
      size_t ob = (size_t)row * N;
#pragma unroll
      for (int n = 0; n < 8; ++n) {
        int col = cb0 + n * 16;
        float sq = fmaxf(xr + c2[col] - 2.f * acc[m][n][j], 0.f);
        out[ob + col] = __expf(-g * __builtin_sqrtf(sq));
      }
    }
  }
}

// Correctness fallback if workspace/shape doesn't fit (slow, fp32 vector path).
__global__ __launch_bounds__(256) void rbf_naive(
    const float* __restrict__ x, const float* __restrict__ cent,
    const float* __restrict__ gamma, float* __restrict__ out, int D, int N) {
  int row = blockIdx.x;
  int col = blockIdx.y * blockDim.x + threadIdx.x;
  extern __shared__ float xs[];
  for (int i = threadIdx.x; i < D; i += blockDim.x)
    xs[i] = x[(size_t)row * D + i];
  __syncthreads();
  if (col >= N) return;
  const float* cp = cent + (size_t)col * D;
  float s = 0.f;
  for (int d = 0; d < D; ++d) {
    float df = xs[d] - cp[d];
    s += df * df;
  }
  out[(size_t)row * N + col] = __expf(-gamma[0] * __builtin_sqrtf(fmaxf(s, 0.f)));
}

extern "C" void kernel_launch(void* const* d_in, const int* in_sizes, int n_in,
                              void* d_out, int out_size, void* d_ws, size_t ws_size,
                              hipStream_t stream) {
  const float* x = (const float*)d_in[0];
  const float* cent = (const float*)d_in[1];
  const float* gamma = (const float*)d_in[2];
  float* out = (float*)d_out;

  const int D = 1024;  // feature dim per the reference
  int Brows = in_sizes[0] / D;
  int C = in_sizes[1] / D;

  size_t xb_bytes = (size_t)Brows * D * 2;
  size_t cb_bytes = (size_t)C * D * 2;
  size_t need = xb_bytes + cb_bytes + (size_t)Brows * 4 + (size_t)C * 4;
  bool can = (ws_size >= need) && (Brows % BM == 0) && (C % BN == 0) &&
             (D % BK == 0) && (D / BK >= 3);

  if (!can) {
    dim3 grid(Brows, (C + 255) / 256);
    hipLaunchKernelGGL(rbf_naive, grid, dim3(256), D * sizeof(float), stream,
                       x, cent, gamma, out, D, C);
    return;
  }

  unsigned short* xb = (unsigned short*)d_ws;
  unsigned short* cb = (unsigned short*)((char*)d_ws + xb_bytes);
  float* x2 = (float*)((char*)d_ws + xb_bytes + cb_bytes);
  float* c2 = x2 + Brows;

  hipLaunchKernelGGL(prep_rows, dim3(Brows), dim3(256), 0, stream, x, xb, x2, D);
  hipLaunchKernelGGL(prep_rows, dim3(C), dim3(256), 0, stream, cent, cb, c2, D);

  int nwg = (Brows / BM) * (C / BN);
  hipLaunchKernelGGL(rbf_gemm, dim3(nwg), dim3(512), 0, stream,
                     xb, cb, x2, c2, gamma, out, Brows, C, D);
}

// Round 4
// 107.028 us; speedup vs baseline: 1.3345x; 1.0117x over previous
//
#include <hip/hip_runtime.h>
#include <stdint.h>

// RBF layer: out[b,c] = exp(-gamma * sqrt(max(||x_b||^2 - 2 x_b.c_c + ||c_c||^2, 0)))
// B=16384, D=1024, C=2048 (fp32 in/out).
// bf16 MFMA GEMM, 256x256 tile, BK=32, 3-buffer LDS ring, COUNTED vmcnt(4),
// fragment loads via INLINE-ASM ds_read_b128 (invisible to SIInsertWaitcnts, so
// the backend cannot insert vmcnt(0) drains); manual lgkmcnt(0)+sched_barrier(0)
// after each pre-MFMA barrier (rule #18). setprio around MFMA clusters.
// Slot-rotation LDS swizzle via pre-swizzled global source. fp32 row-norms from
// original fp32 data; fused sqrt/exp epilogue.

typedef __attribute__((ext_vector_type(8))) short bf16x8;
typedef __attribute__((ext_vector_type(4))) float f32x4;

#define BM 256
#define BN 256
#define BK 32

__device__ __forceinline__ unsigned short f2bf(float f) {
  union { float f; unsigned int u; } c; c.f = f;
  unsigned int u = c.u;
  unsigned int r = (u + 0x7fffu + ((u >> 16) & 1u)) >> 16;  // RNE
  return (unsigned short)r;
}

// One block per row: fp32 -> bf16 convert + fp32 sum-of-squares.
__global__ __launch_bounds__(256) void prep_rows(
    const float* __restrict__ in, unsigned short* __restrict__ ob,
    float* __restrict__ norm, int K) {
  int row = blockIdx.x;
  const float4* rp = (const float4*)(in + (size_t)row * K);
  ushort4* op = (ushort4*)(ob + (size_t)row * K);
  float s = 0.f;
  for (int i = threadIdx.x; i < (K >> 2); i += blockDim.x) {
    float4 v = rp[i];
    s += v.x * v.x + v.y * v.y + v.z * v.z + v.w * v.w;
    ushort4 u;
    u.x = f2bf(v.x); u.y = f2bf(v.y); u.z = f2bf(v.z); u.w = f2bf(v.w);
    op[i] = u;
  }
  for (int off = 32; off > 0; off >>= 1) s += __shfl_down(s, off, 64);
  __shared__ float partial[4];
  int lane = threadIdx.x & 63, wv = threadIdx.x >> 6;
  if (lane == 0) partial[wv] = s;
  __syncthreads();
  if (threadIdx.x == 0) {
    float t = 0.f;
    int nw = (blockDim.x + 63) >> 6;
    for (int w = 0; w < nw; ++w) t += partial[w];
    norm[row] = t;
  }
}

#define GLDS(gptr, lptr)                                                      \
  __builtin_amdgcn_global_load_lds(                                           \
      (const __attribute__((address_space(1))) unsigned int*)(gptr),          \
      (__attribute__((address_space(3))) unsigned int*)(lptr), 16, 0, 0)

// Inline-asm LDS read: byte-address VGPR + compile-time immediate offset.
#define DSR(dst, addr, imm)                                                   \
  asm volatile("ds_read_b128 %0, %1 offset:%c2"                              \
               : "=v"(dst) : "v"(addr), "i"(imm))

#define WAIT_LGKM0()                                                          \
  do {                                                                        \
    asm volatile("s_waitcnt lgkmcnt(0)" ::: "memory");                        \
    __builtin_amdgcn_sched_barrier(0);                                        \
  } while (0)

// 256x256 bf16 GEMM, counted-vmcnt 3-buffer pipeline + fused RBF epilogue.
// A: [M][K] bf16 row-major (x). Bm: [N][K] bf16 row-major (centers).
__global__ __launch_bounds__(512, 2) void rbf_gemm(
    const unsigned short* __restrict__ A, const unsigned short* __restrict__ Bm,
    const float* __restrict__ x2, const float* __restrict__ c2,
    const float* __restrict__ gamma, float* __restrict__ out,
    int M, int N, int K) {
  // 3 buffers x 32KB: per buffer A-tile 16KB (256x32 bf16) then B-tile 16KB.
  // Physical 16B slot p of row r holds logical slot l where p=(l+(r>>1))&3.
  __shared__ __align__(16) unsigned short lds[3 * 16384];

  int nbn = N / BN;
  int nwg = (M / BM) * nbn;
  int bid = blockIdx.x;
  int wg = bid;
  if ((nwg & 7) == 0) {  // XCD-aware swizzle (bijective: nwg % 8 == 0)
    int cpx = nwg >> 3;
    wg = (bid & 7) * cpx + (bid >> 3);
  }
  int bm = wg / nbn, bn = wg % nbn;

  int tid = threadIdx.x;
  int lane = tid & 63, wv = tid >> 6;
  int wm = wv >> 1;   // 0..3 : wave row (64 rows each)
  int wn = wv & 1;    // 0..1 : wave col (128 cols each)
  int l15 = lane & 15, l4 = lane >> 4;

  // ---- staging map: each gload inst covers 128 rows x 64B (8KB) ----
  int lsw = ((tid & 3) - (tid >> 3)) & 3;  // pre-swizzled logical slot
  const unsigned short* AgT =
      A + (size_t)bm * BM * K + (size_t)(tid >> 2) * K + lsw * 8;
  const unsigned short* BgT =
      Bm + (size_t)bn * BN * K + (size_t)(tid >> 2) * K + lsw * 8;
  size_t rstep = (size_t)128 * K;

  // ---- fragment read map (contiguous 1KB per wave -> conflict-free) ----
  int pc = (l4 + (l15 >> 1)) & 3;                       // phys slot this lane
  unsigned aByte = (unsigned)((wm * 64 + l15) * 64 + pc * 16);
  unsigned bByte = (unsigned)(16384 + (wn * 128 + l15) * 64 + pc * 16);
  unsigned ldsBase =
      (unsigned)(size_t)(const __attribute__((address_space(3))) void*)&lds[0];

  f32x4 acc[4][8];
#pragma unroll
  for (int m = 0; m < 4; ++m)
#pragma unroll
    for (int n = 0; n < 8; ++n) acc[m][n] = (f32x4){0.f, 0.f, 0.f, 0.f};

  int nt = K / BK;

  // ---- prologue: stage tiles 0,1 into buffers 0,1 ----
#pragma unroll
  for (int tt = 0; tt < 2; ++tt) {
    unsigned short* base = lds + tt * 16384;
    GLDS(AgT + (size_t)tt * BK, base + tid * 8);
    GLDS(AgT + rstep + (size_t)tt * BK, base + 4096 + tid * 8);
    GLDS(BgT + (size_t)tt * BK, base + 8192 + tid * 8);
    GLDS(BgT + rstep + (size_t)tt * BK, base + 12288 + tid * 8);
  }
  asm volatile("s_waitcnt vmcnt(4)" ::: "memory");  // tile 0 resident
  __builtin_amdgcn_s_barrier();

  int rb = 0;
  for (int t = 0; t < nt; ++t) {
    unsigned bufOff = (unsigned)rb * 32768u;
    int sbi = rb + 2; if (sbi >= 3) sbi -= 3;
    unsigned short* bufS = lds + sbi * 16384;
    size_t ktS = (size_t)(t + 2) * BK;
    bool doStage = (t + 2 < nt);

    unsigned aAd = ldsBase + bufOff + aByte;
    unsigned bAd = ldsBase + bufOff + bByte;

    // ================= phase 0: A(m0-3) x B(n0-3); stage A of t+2 =========
    bf16x8 af0, af1, af2, af3, b0, b1, b2, b3;
    DSR(af0, aAd, 0);    DSR(af1, aAd, 1024);
    DSR(af2, aAd, 2048); DSR(af3, aAd, 3072);
    DSR(b0, bAd, 0);     DSR(b1, bAd, 1024);
    DSR(b2, bAd, 2048);  DSR(b3, bAd, 3072);
    if (doStage) {
      GLDS(AgT + ktS, bufS + tid * 8);
      GLDS(AgT + rstep + ktS, bufS + 4096 + tid * 8);
    }
    __builtin_amdgcn_s_barrier();
    WAIT_LGKM0();
    __builtin_amdgcn_s_setprio(1);
    acc[0][0] = __builtin_amdgcn_mfma_f32_16x16x32_bf16(af0, b0, acc[0][0], 0, 0, 0);
    acc[0][1] = __builtin_amdgcn_mfma_f32_16x16x32_bf16(af0, b1, acc[0][1], 0, 0, 0);
    acc[0][2] = __builtin_amdgcn_mfma_f32_16x16x32_bf16(af0, b2, acc[0][2], 0, 0, 0);
    acc[0][3] = __builtin_amdgcn_mfma_f32_16x16x32_bf16(af0, b3, acc[0][3], 0, 0, 0);
    acc[1][0] = __builtin_amdgcn_mfma_f32_16x16x32_bf16(af1, b0, acc[1][0], 0, 0, 0);
    acc[1][1] = __builtin_amdgcn_mfma_f32_16x16x32_bf16(af1, b1, acc[1][1], 0, 0, 0);
    acc[1][2] = __builtin_amdgcn_mfma_f32_16x16x32_bf16(af1, b2, acc[1][2], 0, 0, 0);
    acc[1][3] = __builtin_amdgcn_mfma_f32_16x16x32_bf16(af1, b3, acc[1][3], 0, 0, 0);
    acc[2][0] = __builtin_amdgcn_mfma_f32_16x16x32_bf16(af2, b0, acc[2][0], 0, 0, 0);
    acc[2][1] = __builtin_amdgcn_mfma_f32_16x16x32_bf16(af2, b1, acc[2][1], 0, 0, 0);
    acc[2][2] = __builtin_amdgcn_mfma_f32_16x16x32_bf16(af2, b2, acc[2][2], 0, 0, 0);
    acc[2][3] = __builtin_amdgcn_mfma_f32_16x16x32_bf16(af2, b3, acc[2][3], 0, 0, 0);
    acc[3][0] = __builtin_amdgcn_mfma_f32_16x16x32_bf16(af3, b0, acc[3][0], 0, 0, 0);
    acc[3][1] = __builtin_amdgcn_mfma_f32_16x16x32_bf16(af3, b1, acc[3][1], 0, 0, 0);
    acc[3][2] = __builtin_amdgcn_mfma_f32_16x16x32_bf16(af3, b2, acc[3][2], 0, 0, 0);
    acc[3][3] = __builtin_amdgcn_mfma_f32_16x16x32_bf16(af3, b3, acc[3][3], 0, 0, 0);
    __builtin_amdgcn_s_setprio(0);
    __builtin_amdgcn_s_barrier();

    // ================= phase 1: A(m0-3) x B(n4-7); stage B of t+2 =========
    bf16x8 b4, b5, b6, b7;
    DSR(b4, bAd, 4096); DSR(b5, bAd, 5120);
    DSR(b6, bAd, 6144); DSR(b7, bAd, 7168);
    if (doStage) {
      GLDS(BgT + ktS, bufS + 8192 + tid * 8);
      GLDS(BgT + rstep + ktS, bufS + 12288 + tid * 8);
    }
    __builtin_amdgcn_s_barrier();
    WAIT_LGKM0();
    __builtin_amdgcn_s_setprio(1);
    acc[0][4] = __builtin_amdgcn_mfma_f32_16x16x32_bf16(af0, b4, acc[0][4], 0, 0, 0);
    acc[0][5] = __builtin_amdgcn_mfma_f32_16x16x32_bf16(af0, b5, acc[0][5], 0, 0, 0);
    acc[0][6] = __builtin_amdgcn_mfma_f32_16x16x32_bf16(af0, b6, acc[0][6], 0, 0, 0);
    acc[0][7] = __builtin_amdgcn_mfma_f32_16x16x32_bf16(af0, b7, acc[0][7], 0, 0, 0);
    acc[1][4] = __builtin_amdgcn_mfma_f32_16x16x32_bf16(af1, b4, acc[1][4], 0, 0, 0);
    acc[1][5] = __builtin_amdgcn_mfma_f32_16x16x32_bf16(af1, b5, acc[1][5], 0, 0, 0);
    acc[1][6] = __builtin_amdgcn_mfma_f32_16x16x32_bf16(af1, b6, acc[1][6], 0, 0, 0);
    acc[1][7] = __builtin_amdgcn_mfma_f32_16x16x32_bf16(af1, b7, acc[1][7], 0, 0, 0);
    acc[2][4] = __builtin_amdgcn_mfma_f32_16x16x32_bf16(af2, b4, acc[2][4], 0, 0, 0);
    acc[2][5] = __builtin_amdgcn_mfma_f32_16x16x32_bf16(af2, b5, acc[2][5], 0, 0, 0);
    acc[2][6] = __builtin_amdgcn_mfma_f32_16x16x32_bf16(af2, b6, acc[2][6], 0, 0, 0);
    acc[2][7] = __builtin_amdgcn_mfma_f32_16x16x32_bf16(af2, b7, acc[2][7], 0, 0, 0);
    acc[3][4] = __builtin_amdgcn_mfma_f32_16x16x32_bf16(af3, b4, acc[3][4], 0, 0, 0);
    acc[3][5] = __builtin_amdgcn_mfma_f32_16x16x32_bf16(af3, b5, acc[3][5], 0, 0, 0);
    acc[3][6] = __builtin_amdgcn_mfma_f32_16x16x32_bf16(af3, b6, acc[3][6], 0, 0, 0);
    acc[3][7] = __builtin_amdgcn_mfma_f32_16x16x32_bf16(af3, b7, acc[3][7], 0, 0, 0);
    __builtin_amdgcn_s_setprio(0);
    // Counted wait: outstanding = S_{t+1}(4) + S_{t+2}(4); vmcnt(4) => t+1 resident.
    if (t < nt - 2) {
      asm volatile("s_waitcnt vmcnt(4)" ::: "memory");
    } else if (t == nt - 2) {
      asm volatile("s_waitcnt vmcnt(0)" ::: "memory");
    }
    __builtin_amdgcn_s_barrier();

    rb++; if (rb == 3) rb = 0;
  }

  // ---- epilogue: C/D layout col = lane&15, row = (lane>>4)*4 + reg ----
  float g = gamma[0];
  int rb0 = bm * BM + wm * 64 + l4 * 4;
  int cb0 = bn * BN + wn * 128 + l15;
#pragma unroll
  for (int m = 0; m < 4; ++m) {
#pragma unroll
    for (int j = 0; j < 4; ++j) {
      int row = rb0 + m * 16 + j;
      float xr = x2[row];
      size_t ob = (size_t)row * N;
#pragma unroll
      for (int n = 0; n < 8; ++n) {
        int col = cb0 + n * 16;
        float sq = fmaxf(xr + c2[col] - 2.f * acc[m][n][j], 0.f);
        out[ob + col] = __expf(-g * __builtin_sqrtf(sq));
      }
    }
  }
}

// Correctness fallback if workspace/shape doesn't fit (slow, fp32 vector path).
__global__ __launch_bounds__(256) void rbf_naive(
    const float* __restrict__ x, const float* __restrict__ cent,
    const float* __restrict__ gamma, float* __restrict__ out, int D, int N) {
  int row = blockIdx.x;
  int col = blockIdx.y * blockDim.x + threadIdx.x;
  extern __shared__ float xs[];
  for (int i = threadIdx.x; i < D; i += blockDim.x)
    xs[i] = x[(size_t)row * D + i];
  __syncthreads();
  if (col >= N) return;
  const float* cp = cent + (size_t)col * D;
  float s = 0.f;
  for (int d = 0; d < D; ++d) {
    float df = xs[d] - cp[d];
    s += df * df;
  }
  out[(size_t)row * N + col] = __expf(-gamma[0] * __builtin_sqrtf(fmaxf(s, 0.f)));
}

extern "C" void kernel_launch(void* const* d_in, const int* in_sizes, int n_in,
                              void* d_out, int out_size, void* d_ws, size_t ws_size,
                              hipStream_t stream) {
  const float* x = (const float*)d_in[0];
  const float* cent = (const float*)d_in[1];
  const float* gamma = (const float*)d_in[2];
  float* out = (float*)d_out;

  const int D = 1024;  // feature dim per the reference
  int Brows = in_sizes[0] / D;
  int C = in_sizes[1] / D;

  size_t xb_bytes = (size_t)Brows * D * 2;
  size_t cb_bytes = (size_t)C * D * 2;
  size_t need = xb_bytes + cb_bytes + (size_t)Brows * 4 + (size_t)C * 4;
  bool can = (ws_size >= need) && (Brows % BM == 0) && (C % BN == 0) &&
             (D % BK == 0) && (D / BK >= 3);

  if (!can) {
    dim3 grid(Brows, (C + 255) / 256);
    hipLaunchKernelGGL(rbf_naive, grid, dim3(256), D * sizeof(float), stream,
                       x, cent, gamma, out, D, C);
    return;
  }

  unsigned short* xb = (unsigned short*)d_ws;
  unsigned short* cb = (unsigned short*)((char*)d_ws + xb_bytes);
  float* x2 = (float*)((char*)d_ws + xb_bytes + cb_bytes);
  float* c2 = x2 + Brows;

  hipLaunchKernelGGL(prep_rows, dim3(Brows), dim3(256), 0, stream, x, xb, x2, D);
  hipLaunchKernelGGL(prep_rows, dim3(C), dim3(256), 0, stream, cent, cb, c2, D);

  int nwg = (Brows / BM) * (C / BN);
  hipLaunchKernelGGL(rbf_gemm, dim3(nwg), dim3(512), 0, stream,
                     xb, cb, x2, c2, gamma, out, Brows, C, D);
}